// Round 1
// baseline (1274.744 us; speedup 1.0000x reference)
//
#include <hip/hip_runtime.h>
#include <math.h>

#define B_      8
#define L_      4096
#define D_      768
#define NB_     8
#define BS_     96
#define NMODES  2049
#define KP      2052          // padded mode stride (16B-aligned rows)
#define PLANE_  ((size_t)B_ * D_ * KP)   // floats per spectrum plane

static const double PI_D = 3.14159265358979323846;

__device__ __forceinline__ float2 cmulf(float2 a, float2 b) {
  return make_float2(a.x * b.x - a.y * b.y, a.x * b.y + a.y * b.x);
}

__device__ __forceinline__ void fma4(float4& a, const float4& u, float w) {
  a.x = fmaf(u.x, w, a.x);
  a.y = fmaf(u.y, w, a.y);
  a.z = fmaf(u.z, w, a.z);
  a.w = fmaf(u.w, w, a.w);
}

// ---------------------------------------------------------------------------
// Kernel 1: forward rFFT(4096, ortho) per (b, d) column.
// Pack x[2n]+i*x[2n+1] -> 2048-pt complex Stockham FFT in LDS -> untangle.
// ---------------------------------------------------------------------------
__global__ __launch_bounds__(256) void fft_fwd(const float* __restrict__ x,
                                               float* __restrict__ SR,
                                               float* __restrict__ SI) {
  __shared__ float2 Sb[2][2048];
  __shared__ float2 TW[1024];
  const int d = blockIdx.x;
  const int b = blockIdx.y;
  const int tid = threadIdx.x;

  // forward twiddles W[j] = exp(-2*pi*i*j/2048)
  for (int j = tid; j < 1024; j += 256) {
    float s, c;
    sincosf(-(float)j * (float)(PI_D / 1024.0), &s, &c);
    TW[j] = make_float2(c, s);
  }

  const float* xb = x + (size_t)b * L_ * D_ + d;
  for (int n = tid; n < 2048; n += 256) {
    Sb[0][n] = make_float2(xb[(size_t)(2 * n) * D_], xb[(size_t)(2 * n + 1) * D_]);
  }
  __syncthreads();

  int src = 0;
  for (int m = 1; m <= 1024; m <<= 1) {
    for (int t = tid; t < 1024; t += 256) {
      int hi = t & ~(m - 1);
      float2 c0 = Sb[src][t];
      float2 c1 = Sb[src][t + 1024];
      float2 sum = make_float2(c0.x + c1.x, c0.y + c1.y);
      float2 dif = make_float2(c0.x - c1.x, c0.y - c1.y);
      Sb[src ^ 1][t + hi] = sum;
      Sb[src ^ 1][t + hi + m] = cmulf(TW[hi], dif);
    }
    src ^= 1;
    __syncthreads();
  }

  // untangle: X[k] = 0.5(Za+conj(Zb)) - 0.5i * e^{-2pi i k/4096} * (Za-conj(Zb))
  float* sr = SR + ((size_t)b * D_ + d) * KP;
  float* si = SI + ((size_t)b * D_ + d) * KP;
  for (int k = tid; k <= 2048; k += 256) {
    int ia = k & 2047;
    int ib = (2048 - k) & 2047;
    float2 Za = Sb[src][ia];
    float2 Zb = Sb[src][ib];
    Zb.y = -Zb.y;  // conj
    float2 sum = make_float2(0.5f * (Za.x + Zb.x), 0.5f * (Za.y + Zb.y));
    float2 dif = make_float2(0.5f * (Za.x - Zb.x), 0.5f * (Za.y - Zb.y));
    float s, c;
    sincosf(-(float)k * (float)(PI_D / 2048.0), &s, &c);
    float2 t = cmulf(make_float2(c, s), dif);
    // X = sum + (-i)*t = {sum.x + t.y, sum.y - t.x}; ortho scale 1/64
    sr[k] = (sum.x + t.y) * 0.015625f;
    si[k] = (sum.y - t.x) * 0.015625f;
  }
}

// ---------------------------------------------------------------------------
// Kernel 2: per-mode block-diagonal complex 2-layer MLP, in-place on SR/SI.
// One wg = (b, block n, 64-mode tile). LDS: A-tile 192x64 + weights 2x96x96.
// ---------------------------------------------------------------------------
__device__ __forceinline__ void gemm_pass(const float (*As)[64],
                                          const float* __restrict__ Wr,
                                          const float* __restrict__ Wi,
                                          int h, int mg, int j0, float4 acc[12]) {
  for (int c = 0; c < 96; ++c) {
    float4 ar = *(const float4*)&As[c][mg * 4];
    float4 ai = *(const float4*)&As[96 + c][mg * 4];
    float4 u, vs;
    if (h) {              // imag outputs: sum_c ai*wr + ar*wi
      u = ai;
      vs = ar;
    } else {              // real outputs: sum_c ar*wr - ai*wi
      u = ar;
      vs = make_float4(-ai.x, -ai.y, -ai.z, -ai.w);
    }
    const float* wrp = Wr + c * 96 + j0;
    const float* wip = Wi + c * 96 + j0;
    float4 wr0 = *(const float4*)(wrp);
    float4 wr1 = *(const float4*)(wrp + 4);
    float4 wr2 = *(const float4*)(wrp + 8);
    float4 wi0 = *(const float4*)(wip);
    float4 wi1 = *(const float4*)(wip + 4);
    float4 wi2 = *(const float4*)(wip + 8);
    fma4(acc[0], u, wr0.x);  fma4(acc[0], vs, wi0.x);
    fma4(acc[1], u, wr0.y);  fma4(acc[1], vs, wi0.y);
    fma4(acc[2], u, wr0.z);  fma4(acc[2], vs, wi0.z);
    fma4(acc[3], u, wr0.w);  fma4(acc[3], vs, wi0.w);
    fma4(acc[4], u, wr1.x);  fma4(acc[4], vs, wi1.x);
    fma4(acc[5], u, wr1.y);  fma4(acc[5], vs, wi1.y);
    fma4(acc[6], u, wr1.z);  fma4(acc[6], vs, wi1.z);
    fma4(acc[7], u, wr1.w);  fma4(acc[7], vs, wi1.w);
    fma4(acc[8], u, wr2.x);  fma4(acc[8], vs, wi2.x);
    fma4(acc[9], u, wr2.y);  fma4(acc[9], vs, wi2.y);
    fma4(acc[10], u, wr2.z); fma4(acc[10], vs, wi2.z);
    fma4(acc[11], u, wr2.w); fma4(acc[11], vs, wi2.w);
  }
}

__global__ __launch_bounds__(256) void mlp(float* __restrict__ SR,
                                           float* __restrict__ SI,
                                           const float* __restrict__ w1,
                                           const float* __restrict__ b1,
                                           const float* __restrict__ w2,
                                           const float* __restrict__ b2) {
  __shared__ __align__(16) float As[192][64];    // rows 0..95 re, 96..191 im
  __shared__ __align__(16) float Ws[2][96 * 96]; // [0]=w_r, [1]=w_i
  const int t0 = blockIdx.x;   // mode tile 0..32
  const int n = blockIdx.y;    // block
  const int b = blockIdx.z;    // batch
  const int tid = threadIdx.x;
  const int k0 = t0 * 64;
  const int mg = tid & 15;         // mode group: 4 modes
  const int cg = tid >> 4;         // col group: 12 cols
  const int h = cg >> 3;           // 0 = real-half cols, 1 = imag-half cols
  const int j0 = (cg & 7) * 12;    // col offset within half

  // ---- load activation tile (192 rows x 64 modes) ----
  for (int i = tid; i < 192 * 16; i += 256) {
    int row = i >> 4;
    int c4 = i & 15;
    int ch = (row < 96) ? row : row - 96;
    const float* plane = (row < 96) ? SR : SI;
    size_t gaddr = ((size_t)b * D_ + n * BS_ + ch) * KP + k0 + c4 * 4;
    int k = k0 + c4 * 4;
    float4 v;
    if (k + 3 < NMODES) {
      v = *(const float4*)(plane + gaddr);
    } else {
      v.x = (k < NMODES) ? plane[gaddr] : 0.f;
      v.y = (k + 1 < NMODES) ? plane[gaddr + 1] : 0.f;
      v.z = (k + 2 < NMODES) ? plane[gaddr + 2] : 0.f;
      v.w = 0.f;
    }
    *(float4*)&As[row][c4 * 4] = v;
  }
  // ---- load layer-1 weights ----
  {
    const float* w1r = w1 + (size_t)n * 96 * 96;
    const float* w1i = w1 + (size_t)(NB_ + n) * 96 * 96;
    for (int i = tid; i < 2304; i += 256) {
      ((float4*)Ws[0])[i] = ((const float4*)w1r)[i];
      ((float4*)Ws[1])[i] = ((const float4*)w1i)[i];
    }
  }
  // biases for this thread's 12 cols
  float bias1[12], bias2[12];
  for (int jj = 0; jj < 12; ++jj) {
    bias1[jj] = b1[(size_t)(h * NB_ + n) * 96 + j0 + jj];
    bias2[jj] = b2[(size_t)(h * NB_ + n) * 96 + j0 + jj];
  }
  __syncthreads();

  // ---- layer 1 ----
  float4 acc[12];
  for (int jj = 0; jj < 12; ++jj)
    acc[jj] = make_float4(bias1[jj], bias1[jj], bias1[jj], bias1[jj]);
  gemm_pass(As, Ws[0], Ws[1], h, mg, j0, acc);
  // relu
  for (int jj = 0; jj < 12; ++jj) {
    acc[jj].x = fmaxf(acc[jj].x, 0.f);
    acc[jj].y = fmaxf(acc[jj].y, 0.f);
    acc[jj].z = fmaxf(acc[jj].z, 0.f);
    acc[jj].w = fmaxf(acc[jj].w, 0.f);
  }
  __syncthreads();  // everyone done reading As / Ws

  // store O1 over As: row = h*96 + (j0+jj), cols mg*4..+3
  for (int jj = 0; jj < 12; ++jj)
    *(float4*)&As[h * 96 + j0 + jj][mg * 4] = acc[jj];
  // restage layer-2 weights
  {
    const float* w2r = w2 + (size_t)n * 96 * 96;
    const float* w2i = w2 + (size_t)(NB_ + n) * 96 * 96;
    for (int i = tid; i < 2304; i += 256) {
      ((float4*)Ws[0])[i] = ((const float4*)w2r)[i];
      ((float4*)Ws[1])[i] = ((const float4*)w2i)[i];
    }
  }
  __syncthreads();

  // ---- layer 2 ----
  float4 acc2[12];
  for (int jj = 0; jj < 12; ++jj)
    acc2[jj] = make_float4(bias2[jj], bias2[jj], bias2[jj], bias2[jj]);
  gemm_pass(As, Ws[0], Ws[1], h, mg, j0, acc2);

  // softshrink + in-place store
  float* plane = h ? SI : SR;
  for (int jj = 0; jj < 12; ++jj) {
    float4 v = acc2[jj];
    float4 r;
    float t;
    t = fabsf(v.x) - 0.01f; r.x = (t > 0.f) ? copysignf(t, v.x) : 0.f;
    t = fabsf(v.y) - 0.01f; r.y = (t > 0.f) ? copysignf(t, v.y) : 0.f;
    t = fabsf(v.z) - 0.01f; r.z = (t > 0.f) ? copysignf(t, v.z) : 0.f;
    t = fabsf(v.w) - 0.01f; r.w = (t > 0.f) ? copysignf(t, v.w) : 0.f;
    size_t gaddr = ((size_t)b * D_ + n * BS_ + j0 + jj) * KP + k0 + mg * 4;
    int k = k0 + mg * 4;
    if (k + 3 < NMODES) {
      *(float4*)(plane + gaddr) = r;
    } else {
      if (k < NMODES) plane[gaddr] = r.x;
      if (k + 1 < NMODES) plane[gaddr + 1] = r.y;
      if (k + 2 < NMODES) plane[gaddr + 2] = r.z;
      if (k + 3 < NMODES) plane[gaddr + 3] = r.w;
    }
  }
}

// ---------------------------------------------------------------------------
// Kernel 3: inverse rFFT(4096, ortho) per (b, d) + residual add.
// ---------------------------------------------------------------------------
__global__ __launch_bounds__(256) void fft_inv(const float* __restrict__ SR,
                                               const float* __restrict__ SI,
                                               const float* __restrict__ x,
                                               float* __restrict__ y) {
  __shared__ float2 Sb[2][2048];
  __shared__ float2 TW[1024];
  const int d = blockIdx.x;
  const int b = blockIdx.y;
  const int tid = threadIdx.x;

  // inverse twiddles W[j] = exp(+2*pi*i*j/2048)
  for (int j = tid; j < 1024; j += 256) {
    float s, c;
    sincosf((float)j * (float)(PI_D / 1024.0), &s, &c);
    TW[j] = make_float2(c, s);
  }

  const float* sr = SR + ((size_t)b * D_ + d) * KP;
  const float* si = SI + ((size_t)b * D_ + d) * KP;
  for (int k = tid; k < 2048; k += 256) {
    float2 z;
    if (k == 0) {
      // E0 = (ReX0 + ReXM)/2, O0 = (ReX0 - ReXM)/2 (imag ignored, = pocketfft)
      float x0 = sr[0];
      float xm = sr[2048];
      z = make_float2(0.5f * (x0 + xm), 0.5f * (x0 - xm));
    } else {
      float2 Xk = make_float2(sr[k], si[k]);
      float2 Xm = make_float2(sr[2048 - k], -si[2048 - k]);  // conj(X[M-k])
      float2 E = make_float2(0.5f * (Xk.x + Xm.x), 0.5f * (Xk.y + Xm.y));
      float2 Dm = make_float2(0.5f * (Xk.x - Xm.x), 0.5f * (Xk.y - Xm.y));
      float s, c;
      sincosf((float)k * (float)(PI_D / 2048.0), &s, &c);
      float2 O = cmulf(make_float2(c, s), Dm);
      // Z = E + i*O
      z = make_float2(E.x - O.y, E.y + O.x);
    }
    Sb[0][k] = z;
  }
  __syncthreads();

  int src = 0;
  for (int m = 1; m <= 1024; m <<= 1) {
    for (int t = tid; t < 1024; t += 256) {
      int hi = t & ~(m - 1);
      float2 c0 = Sb[src][t];
      float2 c1 = Sb[src][t + 1024];
      float2 sum = make_float2(c0.x + c1.x, c0.y + c1.y);
      float2 dif = make_float2(c0.x - c1.x, c0.y - c1.y);
      Sb[src ^ 1][t + hi] = sum;
      Sb[src ^ 1][t + hi + m] = cmulf(TW[hi], dif);
    }
    src ^= 1;
    __syncthreads();
  }

  const float* xb = x + (size_t)b * L_ * D_ + d;
  float* yb = y + (size_t)b * L_ * D_ + d;
  for (int n = tid; n < 2048; n += 256) {
    float2 z = Sb[src][n];
    size_t a0 = (size_t)(2 * n) * D_;
    yb[a0] = xb[a0] + 0.03125f * z.x;        // 2/sqrt(4096)
    yb[a0 + D_] = xb[a0 + D_] + 0.03125f * z.y;
  }
}

// ---------------------------------------------------------------------------
extern "C" void kernel_launch(void* const* d_in, const int* in_sizes, int n_in,
                              void* d_out, int out_size, void* d_ws, size_t ws_size,
                              hipStream_t stream) {
  (void)in_sizes; (void)n_in; (void)out_size; (void)ws_size;
  const float* x = (const float*)d_in[0];
  const float* w1 = (const float*)d_in[1];
  const float* b1 = (const float*)d_in[2];
  const float* w2 = (const float*)d_in[3];
  const float* b2 = (const float*)d_in[4];
  float* SR = (float*)d_ws;
  float* SI = SR + PLANE_;
  float* y = (float*)d_out;

  fft_fwd<<<dim3(D_, B_), 256, 0, stream>>>(x, SR, SI);
  mlp<<<dim3(33, NB_, B_), 256, 0, stream>>>(SR, SI, w1, b1, w2, b2);
  fft_inv<<<dim3(D_, B_), 256, 0, stream>>>(SR, SI, x, y);
}

// Round 2
// 762.388 us; speedup vs baseline: 1.6720x; 1.6720x over previous
//
#include <hip/hip_runtime.h>
#include <math.h>

#define B_      8
#define L_      4096
#define D_      768
#define NB_     8
#define BS_     96
#define NMODES  2049
#define KP      2052          // padded mode stride (16B-aligned rows)
#define PLANE_  ((size_t)B_ * D_ * KP)   // floats per spectrum plane

static const double PI_D = 3.14159265358979323846;

__device__ __forceinline__ float2 cmulf(float2 a, float2 b) {
  return make_float2(a.x * b.x - a.y * b.y, a.x * b.y + a.y * b.x);
}

__device__ __forceinline__ void fma4(float4& a, const float4& u, float w) {
  a.x = fmaf(u.x, w, a.x);
  a.y = fmaf(u.y, w, a.y);
  a.z = fmaf(u.z, w, a.z);
  a.w = fmaf(u.w, w, a.w);
}

// ---------------------------------------------------------------------------
// Transpose x (B,L,D) -> T (B,D,L). 64x64 LDS tiles, both sides coalesced.
// ---------------------------------------------------------------------------
__global__ __launch_bounds__(256) void transpose_fwd(const float* __restrict__ in,
                                                     float* __restrict__ out) {
  __shared__ float tile[64][65];
  const int b = blockIdx.z;
  const int d0 = blockIdx.x * 64;
  const int l0 = blockIdx.y * 64;
  const int tx = threadIdx.x & 63;
  const int ty = threadIdx.x >> 6;
  const float* ib = in + (size_t)b * L_ * D_;
  for (int r = ty; r < 64; r += 4)
    tile[r][tx] = ib[(size_t)(l0 + r) * D_ + d0 + tx];   // row r = l, col tx = d
  __syncthreads();
  float* ob = out + (size_t)b * D_ * L_;
  for (int r = ty; r < 64; r += 4)
    ob[(size_t)(d0 + r) * L_ + l0 + tx] = tile[tx][r];
}

// ---------------------------------------------------------------------------
// Transpose-back + residual: y[b][l][d] = x[b][l][d] + T[b][d][l]
// ---------------------------------------------------------------------------
__global__ __launch_bounds__(256) void transpose_add(const float* __restrict__ T,
                                                     const float* __restrict__ x,
                                                     float* __restrict__ y) {
  __shared__ float tile[64][65];
  const int b = blockIdx.z;
  const int d0 = blockIdx.x * 64;
  const int l0 = blockIdx.y * 64;
  const int tx = threadIdx.x & 63;
  const int ty = threadIdx.x >> 6;
  const float* Tb = T + (size_t)b * D_ * L_;
  for (int r = ty; r < 64; r += 4)
    tile[r][tx] = Tb[(size_t)(d0 + r) * L_ + l0 + tx];   // row r = d, col tx = l
  __syncthreads();
  const float* xb = x + (size_t)b * L_ * D_;
  float* yb = y + (size_t)b * L_ * D_;
  for (int r = ty; r < 64; r += 4) {
    size_t a = (size_t)(l0 + r) * D_ + d0 + tx;
    yb[a] = xb[a] + tile[tx][r];
  }
}

// ---------------------------------------------------------------------------
// Kernel 1: forward rFFT(4096, ortho) per (b, d) row of T (contiguous).
// Pack x[2n]+i*x[2n+1] -> 2048-pt complex Stockham FFT in LDS -> untangle.
// ---------------------------------------------------------------------------
__global__ __launch_bounds__(256) void fft_fwd(const float* __restrict__ T,
                                               float* __restrict__ SR,
                                               float* __restrict__ SI) {
  __shared__ float2 Sb[2][2048];
  __shared__ float2 TW[1024];
  const int d = blockIdx.x;
  const int b = blockIdx.y;
  const int tid = threadIdx.x;

  // forward twiddles W[j] = exp(-2*pi*i*j/2048)
  for (int j = tid; j < 1024; j += 256) {
    float s, c;
    sincosf(-(float)j * (float)(PI_D / 1024.0), &s, &c);
    TW[j] = make_float2(c, s);
  }

  const float2* xr = (const float2*)(T + ((size_t)b * D_ + d) * L_);
  for (int n = tid; n < 2048; n += 256)
    Sb[0][n] = xr[n];                 // (x[2n], x[2n+1]) packed complex
  __syncthreads();

  int src = 0;
  for (int m = 1; m <= 1024; m <<= 1) {
    for (int t = tid; t < 1024; t += 256) {
      int hi = t & ~(m - 1);
      float2 c0 = Sb[src][t];
      float2 c1 = Sb[src][t + 1024];
      float2 sum = make_float2(c0.x + c1.x, c0.y + c1.y);
      float2 dif = make_float2(c0.x - c1.x, c0.y - c1.y);
      Sb[src ^ 1][t + hi] = sum;
      Sb[src ^ 1][t + hi + m] = cmulf(TW[hi], dif);
    }
    src ^= 1;
    __syncthreads();
  }

  // untangle: X[k] = 0.5(Za+conj(Zb)) - 0.5i * e^{-2pi i k/4096} * (Za-conj(Zb))
  float* sr = SR + ((size_t)b * D_ + d) * KP;
  float* si = SI + ((size_t)b * D_ + d) * KP;
  for (int k = tid; k <= 2048; k += 256) {
    int ia = k & 2047;
    int ib = (2048 - k) & 2047;
    float2 Za = Sb[src][ia];
    float2 Zb = Sb[src][ib];
    Zb.y = -Zb.y;  // conj
    float2 sum = make_float2(0.5f * (Za.x + Zb.x), 0.5f * (Za.y + Zb.y));
    float2 dif = make_float2(0.5f * (Za.x - Zb.x), 0.5f * (Za.y - Zb.y));
    float s, c;
    sincosf(-(float)k * (float)(PI_D / 2048.0), &s, &c);
    float2 t = cmulf(make_float2(c, s), dif);
    // X = sum + (-i)*t = {sum.x + t.y, sum.y - t.x}; ortho scale 1/64
    sr[k] = (sum.x + t.y) * 0.015625f;
    si[k] = (sum.y - t.x) * 0.015625f;
  }
}

// ---------------------------------------------------------------------------
// Kernel 2: per-mode block-diagonal complex 2-layer MLP, in-place on SR/SI.
// One wg = (b, block n, 64-mode tile). LDS: A-tile 192x64 + weights 2x96x96.
// ---------------------------------------------------------------------------
__device__ __forceinline__ void gemm_pass(const float (*As)[64],
                                          const float* __restrict__ Wr,
                                          const float* __restrict__ Wi,
                                          int h, int mg, int j0, float4 acc[12]) {
  for (int c = 0; c < 96; ++c) {
    float4 ar = *(const float4*)&As[c][mg * 4];
    float4 ai = *(const float4*)&As[96 + c][mg * 4];
    float4 u, vs;
    if (h) {              // imag outputs: sum_c ai*wr + ar*wi
      u = ai;
      vs = ar;
    } else {              // real outputs: sum_c ar*wr - ai*wi
      u = ar;
      vs = make_float4(-ai.x, -ai.y, -ai.z, -ai.w);
    }
    const float* wrp = Wr + c * 96 + j0;
    const float* wip = Wi + c * 96 + j0;
    float4 wr0 = *(const float4*)(wrp);
    float4 wr1 = *(const float4*)(wrp + 4);
    float4 wr2 = *(const float4*)(wrp + 8);
    float4 wi0 = *(const float4*)(wip);
    float4 wi1 = *(const float4*)(wip + 4);
    float4 wi2 = *(const float4*)(wip + 8);
    fma4(acc[0], u, wr0.x);  fma4(acc[0], vs, wi0.x);
    fma4(acc[1], u, wr0.y);  fma4(acc[1], vs, wi0.y);
    fma4(acc[2], u, wr0.z);  fma4(acc[2], vs, wi0.z);
    fma4(acc[3], u, wr0.w);  fma4(acc[3], vs, wi0.w);
    fma4(acc[4], u, wr1.x);  fma4(acc[4], vs, wi1.x);
    fma4(acc[5], u, wr1.y);  fma4(acc[5], vs, wi1.y);
    fma4(acc[6], u, wr1.z);  fma4(acc[6], vs, wi1.z);
    fma4(acc[7], u, wr1.w);  fma4(acc[7], vs, wi1.w);
    fma4(acc[8], u, wr2.x);  fma4(acc[8], vs, wi2.x);
    fma4(acc[9], u, wr2.y);  fma4(acc[9], vs, wi2.y);
    fma4(acc[10], u, wr2.z); fma4(acc[10], vs, wi2.z);
    fma4(acc[11], u, wr2.w); fma4(acc[11], vs, wi2.w);
  }
}

__global__ __launch_bounds__(256) void mlp(float* __restrict__ SR,
                                           float* __restrict__ SI,
                                           const float* __restrict__ w1,
                                           const float* __restrict__ b1,
                                           const float* __restrict__ w2,
                                           const float* __restrict__ b2) {
  __shared__ __align__(16) float As[192][64];    // rows 0..95 re, 96..191 im
  __shared__ __align__(16) float Ws[2][96 * 96]; // [0]=w_r, [1]=w_i
  const int t0 = blockIdx.x;   // mode tile 0..32
  const int n = blockIdx.y;    // block
  const int b = blockIdx.z;    // batch
  const int tid = threadIdx.x;
  const int k0 = t0 * 64;
  const int mg = tid & 15;         // mode group: 4 modes
  const int cg = tid >> 4;         // col group: 12 cols
  const int h = cg >> 3;           // 0 = real-half cols, 1 = imag-half cols
  const int j0 = (cg & 7) * 12;    // col offset within half

  // ---- load activation tile (192 rows x 64 modes) ----
  for (int i = tid; i < 192 * 16; i += 256) {
    int row = i >> 4;
    int c4 = i & 15;
    int ch = (row < 96) ? row : row - 96;
    const float* plane = (row < 96) ? SR : SI;
    size_t gaddr = ((size_t)b * D_ + n * BS_ + ch) * KP + k0 + c4 * 4;
    int k = k0 + c4 * 4;
    float4 v;
    if (k + 3 < NMODES) {
      v = *(const float4*)(plane + gaddr);
    } else {
      v.x = (k < NMODES) ? plane[gaddr] : 0.f;
      v.y = (k + 1 < NMODES) ? plane[gaddr + 1] : 0.f;
      v.z = (k + 2 < NMODES) ? plane[gaddr + 2] : 0.f;
      v.w = 0.f;
    }
    *(float4*)&As[row][c4 * 4] = v;
  }
  // ---- load layer-1 weights ----
  {
    const float* w1r = w1 + (size_t)n * 96 * 96;
    const float* w1i = w1 + (size_t)(NB_ + n) * 96 * 96;
    for (int i = tid; i < 2304; i += 256) {
      ((float4*)Ws[0])[i] = ((const float4*)w1r)[i];
      ((float4*)Ws[1])[i] = ((const float4*)w1i)[i];
    }
  }
  // biases for this thread's 12 cols
  float bias1[12], bias2[12];
  for (int jj = 0; jj < 12; ++jj) {
    bias1[jj] = b1[(size_t)(h * NB_ + n) * 96 + j0 + jj];
    bias2[jj] = b2[(size_t)(h * NB_ + n) * 96 + j0 + jj];
  }
  __syncthreads();

  // ---- layer 1 ----
  float4 acc[12];
  for (int jj = 0; jj < 12; ++jj)
    acc[jj] = make_float4(bias1[jj], bias1[jj], bias1[jj], bias1[jj]);
  gemm_pass(As, Ws[0], Ws[1], h, mg, j0, acc);
  // relu
  for (int jj = 0; jj < 12; ++jj) {
    acc[jj].x = fmaxf(acc[jj].x, 0.f);
    acc[jj].y = fmaxf(acc[jj].y, 0.f);
    acc[jj].z = fmaxf(acc[jj].z, 0.f);
    acc[jj].w = fmaxf(acc[jj].w, 0.f);
  }
  __syncthreads();  // everyone done reading As / Ws

  // store O1 over As: row = h*96 + (j0+jj), cols mg*4..+3
  for (int jj = 0; jj < 12; ++jj)
    *(float4*)&As[h * 96 + j0 + jj][mg * 4] = acc[jj];
  // restage layer-2 weights
  {
    const float* w2r = w2 + (size_t)n * 96 * 96;
    const float* w2i = w2 + (size_t)(NB_ + n) * 96 * 96;
    for (int i = tid; i < 2304; i += 256) {
      ((float4*)Ws[0])[i] = ((const float4*)w2r)[i];
      ((float4*)Ws[1])[i] = ((const float4*)w2i)[i];
    }
  }
  __syncthreads();

  // ---- layer 2 ----
  float4 acc2[12];
  for (int jj = 0; jj < 12; ++jj)
    acc2[jj] = make_float4(bias2[jj], bias2[jj], bias2[jj], bias2[jj]);
  gemm_pass(As, Ws[0], Ws[1], h, mg, j0, acc2);

  // softshrink + in-place store
  float* plane = h ? SI : SR;
  for (int jj = 0; jj < 12; ++jj) {
    float4 v = acc2[jj];
    float4 r;
    float t;
    t = fabsf(v.x) - 0.01f; r.x = (t > 0.f) ? copysignf(t, v.x) : 0.f;
    t = fabsf(v.y) - 0.01f; r.y = (t > 0.f) ? copysignf(t, v.y) : 0.f;
    t = fabsf(v.z) - 0.01f; r.z = (t > 0.f) ? copysignf(t, v.z) : 0.f;
    t = fabsf(v.w) - 0.01f; r.w = (t > 0.f) ? copysignf(t, v.w) : 0.f;
    size_t gaddr = ((size_t)b * D_ + n * BS_ + j0 + jj) * KP + k0 + mg * 4;
    int k = k0 + mg * 4;
    if (k + 3 < NMODES) {
      *(float4*)(plane + gaddr) = r;
    } else {
      if (k < NMODES) plane[gaddr] = r.x;
      if (k + 1 < NMODES) plane[gaddr + 1] = r.y;
      if (k + 2 < NMODES) plane[gaddr + 2] = r.z;
      if (k + 3 < NMODES) plane[gaddr + 3] = r.w;
    }
  }
}

// ---------------------------------------------------------------------------
// Kernel 3: inverse rFFT(4096, ortho) per (b, d); writes scaled row into T.
// ---------------------------------------------------------------------------
__global__ __launch_bounds__(256) void fft_inv(const float* __restrict__ SR,
                                               const float* __restrict__ SI,
                                               float* __restrict__ T) {
  __shared__ float2 Sb[2][2048];
  __shared__ float2 TW[1024];
  const int d = blockIdx.x;
  const int b = blockIdx.y;
  const int tid = threadIdx.x;

  // inverse twiddles W[j] = exp(+2*pi*i*j/2048)
  for (int j = tid; j < 1024; j += 256) {
    float s, c;
    sincosf((float)j * (float)(PI_D / 1024.0), &s, &c);
    TW[j] = make_float2(c, s);
  }

  const float* sr = SR + ((size_t)b * D_ + d) * KP;
  const float* si = SI + ((size_t)b * D_ + d) * KP;
  for (int k = tid; k < 2048; k += 256) {
    float2 z;
    if (k == 0) {
      // E0 = (ReX0 + ReXM)/2, O0 = (ReX0 - ReXM)/2 (imag ignored, = pocketfft)
      float x0 = sr[0];
      float xm = sr[2048];
      z = make_float2(0.5f * (x0 + xm), 0.5f * (x0 - xm));
    } else {
      float2 Xk = make_float2(sr[k], si[k]);
      float2 Xm = make_float2(sr[2048 - k], -si[2048 - k]);  // conj(X[M-k])
      float2 E = make_float2(0.5f * (Xk.x + Xm.x), 0.5f * (Xk.y + Xm.y));
      float2 Dm = make_float2(0.5f * (Xk.x - Xm.x), 0.5f * (Xk.y - Xm.y));
      float s, c;
      sincosf((float)k * (float)(PI_D / 2048.0), &s, &c);
      float2 O = cmulf(make_float2(c, s), Dm);
      // Z = E + i*O
      z = make_float2(E.x - O.y, E.y + O.x);
    }
    Sb[0][k] = z;
  }
  __syncthreads();

  int src = 0;
  for (int m = 1; m <= 1024; m <<= 1) {
    for (int t = tid; t < 1024; t += 256) {
      int hi = t & ~(m - 1);
      float2 c0 = Sb[src][t];
      float2 c1 = Sb[src][t + 1024];
      float2 sum = make_float2(c0.x + c1.x, c0.y + c1.y);
      float2 dif = make_float2(c0.x - c1.x, c0.y - c1.y);
      Sb[src ^ 1][t + hi] = sum;
      Sb[src ^ 1][t + hi + m] = cmulf(TW[hi], dif);
    }
    src ^= 1;
    __syncthreads();
  }

  float2* tb = (float2*)(T + ((size_t)b * D_ + d) * L_);
  for (int n = tid; n < 2048; n += 256) {
    float2 z = Sb[src][n];
    tb[n] = make_float2(0.03125f * z.x, 0.03125f * z.y);  // 2/sqrt(4096)
  }
}

// ---------------------------------------------------------------------------
extern "C" void kernel_launch(void* const* d_in, const int* in_sizes, int n_in,
                              void* d_out, int out_size, void* d_ws, size_t ws_size,
                              hipStream_t stream) {
  (void)in_sizes; (void)n_in; (void)out_size; (void)ws_size;
  const float* x = (const float*)d_in[0];
  const float* w1 = (const float*)d_in[1];
  const float* b1 = (const float*)d_in[2];
  const float* w2 = (const float*)d_in[3];
  const float* b2 = (const float*)d_in[4];
  float* SR = (float*)d_ws;
  float* SI = SR + PLANE_;
  float* T = SI + PLANE_;          // (B,D,L) scratch; xt and yt alias here
  float* y = (float*)d_out;

  transpose_fwd<<<dim3(D_ / 64, L_ / 64, B_), 256, 0, stream>>>(x, T);
  fft_fwd<<<dim3(D_, B_), 256, 0, stream>>>(T, SR, SI);
  mlp<<<dim3(33, NB_, B_), 256, 0, stream>>>(SR, SI, w1, b1, w2, b2);
  fft_inv<<<dim3(D_, B_), 256, 0, stream>>>(SR, SI, T);
  transpose_add<<<dim3(D_ / 64, L_ / 64, B_), 256, 0, stream>>>(T, x, y);
}

// Round 3
// 480.653 us; speedup vs baseline: 2.6521x; 1.5862x over previous
//
#include <hip/hip_runtime.h>
#include <math.h>

#define B_      8
#define L_      4096
#define D_      768
#define NB_     8
#define BS_     96
#define NMODES  2049
#define KPB     2112                      // bf16 plane mode stride
#define PLN     ((size_t)B_ * D_ * KPB)   // elems per bf16 spectrum plane
#define WKS     104                       // WT row stride (k padded)
#define ASTR    200                       // As row stride (192 + 8 pad)

static const double PI_D = 3.14159265358979323846;

typedef __attribute__((ext_vector_type(8))) short short8v;
typedef __attribute__((ext_vector_type(8))) unsigned short ushort8v;
typedef __attribute__((ext_vector_type(4))) unsigned short ushort4v;
typedef __attribute__((ext_vector_type(4))) unsigned int uint4v;
typedef __attribute__((ext_vector_type(4))) float f32x4;

__device__ __forceinline__ unsigned short f2bf(float f) {
  union { float f; unsigned u; } v; v.f = f;
  unsigned r = v.u + 0x7FFF + ((v.u >> 16) & 1);   // round-nearest-even
  return (unsigned short)(r >> 16);
}
__device__ __forceinline__ float bf2f(unsigned short h) {
  union { unsigned u; float f; } v; v.u = ((unsigned)h) << 16;
  return v.f;
}

__device__ __forceinline__ float2 cmulf(float2 a, float2 b) {
  return make_float2(a.x * b.x - a.y * b.y, a.x * b.y + a.y * b.x);
}

// ---------------------------------------------------------------------------
// Weight prep: w[k][o] (f32) -> WT[o][k] (bf16, row stride WKS). 32 wgs.
// id = (layer*2 + h)*8 + n
// ---------------------------------------------------------------------------
__global__ __launch_bounds__(256) void prep_weights(const float* __restrict__ w1,
                                                    const float* __restrict__ w2,
                                                    unsigned short* __restrict__ WTg) {
  __shared__ float t[96][97];
  const int id = blockIdx.x;
  const int layer = id >> 4;
  const int hn = id & 15;                     // h*8 + n
  const int tid = threadIdx.x;
  const float* src = (layer ? w2 : w1) + (size_t)hn * 9216;
  for (int it = tid; it < 9216; it += 256) {
    int i = it / 96, o = it - i * 96;
    t[i][o] = src[it];
  }
  __syncthreads();
  unsigned short* dst = WTg + (size_t)id * (96 * WKS);
  for (int it = tid; it < 96 * WKS; it += 256) {
    int o = it / WKS, k = it - o * WKS;
    dst[it] = f2bf(k < 96 ? t[k][o] : 0.f);
  }
}

// ---------------------------------------------------------------------------
// Transpose x (B,L,D) -> T (B,D,L). 64x64 LDS tiles, both sides coalesced.
// ---------------------------------------------------------------------------
__global__ __launch_bounds__(256) void transpose_fwd(const float* __restrict__ in,
                                                     float* __restrict__ out) {
  __shared__ float tile[64][65];
  const int b = blockIdx.z;
  const int d0 = blockIdx.x * 64;
  const int l0 = blockIdx.y * 64;
  const int tx = threadIdx.x & 63;
  const int ty = threadIdx.x >> 6;
  const float* ib = in + (size_t)b * L_ * D_;
  for (int r = ty; r < 64; r += 4)
    tile[r][tx] = ib[(size_t)(l0 + r) * D_ + d0 + tx];
  __syncthreads();
  float* ob = out + (size_t)b * D_ * L_;
  for (int r = ty; r < 64; r += 4)
    ob[(size_t)(d0 + r) * L_ + l0 + tx] = tile[tx][r];
}

// ---------------------------------------------------------------------------
// Transpose-back + residual: y[b][l][d] = x[b][l][d] + T[b][d][l]
// ---------------------------------------------------------------------------
__global__ __launch_bounds__(256) void transpose_add(const float* __restrict__ T,
                                                     const float* __restrict__ x,
                                                     float* __restrict__ y) {
  __shared__ float tile[64][65];
  const int b = blockIdx.z;
  const int d0 = blockIdx.x * 64;
  const int l0 = blockIdx.y * 64;
  const int tx = threadIdx.x & 63;
  const int ty = threadIdx.x >> 6;
  const float* Tb = T + (size_t)b * D_ * L_;
  for (int r = ty; r < 64; r += 4)
    tile[r][tx] = Tb[(size_t)(d0 + r) * L_ + l0 + tx];
  __syncthreads();
  const float* xb = x + (size_t)b * L_ * D_;
  float* yb = y + (size_t)b * L_ * D_;
  for (int r = ty; r < 64; r += 4) {
    size_t a = (size_t)(l0 + r) * D_ + d0 + tx;
    yb[a] = xb[a] + tile[tx][r];
  }
}

// ---------------------------------------------------------------------------
// Forward rFFT(4096, ortho) per (b,d) row of T; bf16 spectrum out.
// ---------------------------------------------------------------------------
__global__ __launch_bounds__(256) void fft_fwd(const float* __restrict__ T,
                                               unsigned short* __restrict__ SRb,
                                               unsigned short* __restrict__ SIb) {
  __shared__ float2 Sb[2][2048];
  __shared__ float2 TW[1024];
  const int d = blockIdx.x;
  const int b = blockIdx.y;
  const int tid = threadIdx.x;

  for (int j = tid; j < 1024; j += 256) {
    float s, c;
    sincosf(-(float)j * (float)(PI_D / 1024.0), &s, &c);
    TW[j] = make_float2(c, s);
  }

  const float2* xr = (const float2*)(T + ((size_t)b * D_ + d) * L_);
  for (int n = tid; n < 2048; n += 256)
    Sb[0][n] = xr[n];
  __syncthreads();

  int src = 0;
  for (int m = 1; m <= 1024; m <<= 1) {
    for (int t = tid; t < 1024; t += 256) {
      int hi = t & ~(m - 1);
      float2 c0 = Sb[src][t];
      float2 c1 = Sb[src][t + 1024];
      float2 sum = make_float2(c0.x + c1.x, c0.y + c1.y);
      float2 dif = make_float2(c0.x - c1.x, c0.y - c1.y);
      Sb[src ^ 1][t + hi] = sum;
      Sb[src ^ 1][t + hi + m] = cmulf(TW[hi], dif);
    }
    src ^= 1;
    __syncthreads();
  }

  unsigned short* sr = SRb + ((size_t)b * D_ + d) * KPB;
  unsigned short* si = SIb + ((size_t)b * D_ + d) * KPB;
  for (int k = tid; k <= 2048; k += 256) {
    int ia = k & 2047;
    int ib = (2048 - k) & 2047;
    float2 Za = Sb[src][ia];
    float2 Zb = Sb[src][ib];
    Zb.y = -Zb.y;
    float2 sum = make_float2(0.5f * (Za.x + Zb.x), 0.5f * (Za.y + Zb.y));
    float2 dif = make_float2(0.5f * (Za.x - Zb.x), 0.5f * (Za.y - Zb.y));
    float s, c;
    sincosf(-(float)k * (float)(PI_D / 2048.0), &s, &c);
    float2 t = cmulf(make_float2(c, s), dif);
    sr[k] = f2bf((sum.x + t.y) * 0.015625f);
    si[k] = f2bf((sum.y - t.x) * 0.015625f);
  }
}

// ---------------------------------------------------------------------------
// MFMA MLP. wg = (64-mode tile, block n, batch b), 256 thr / 4 waves.
// As views: layer operand [64 modes][ASTR] (k = [re ch | im ch]),
//           out staging   [192 ch][72 modes].
// ---------------------------------------------------------------------------
__device__ __forceinline__ void do_layer(const short* As, const short* Wt0,
                                         const short* Wt1, int wave, int lane,
                                         f32x4 P[6], f32x4 Q[6], f32x4 R[6],
                                         f32x4 S[6]) {
  const int l15 = lane & 15, kg = lane >> 4;
  const int arow = (wave * 16 + l15) * ASTR;
#pragma unroll
  for (int ks = 0; ks < 3; ++ks) {
    const int ak = ks * 32 + kg * 8;
    short8v axr = *(const short8v*)&As[arow + ak];
    short8v axi = *(const short8v*)&As[arow + 96 + ak];
#pragma unroll
    for (int nf = 0; nf < 6; ++nf) {
      const int brow = (nf * 16 + l15) * WKS + ak;
      short8v bwr = *(const short8v*)&Wt0[brow];
      short8v bwi = *(const short8v*)&Wt1[brow];
      P[nf] = __builtin_amdgcn_mfma_f32_16x16x32_bf16(axr, bwr, P[nf], 0, 0, 0);
      Q[nf] = __builtin_amdgcn_mfma_f32_16x16x32_bf16(axi, bwi, Q[nf], 0, 0, 0);
      R[nf] = __builtin_amdgcn_mfma_f32_16x16x32_bf16(axi, bwr, R[nf], 0, 0, 0);
      S[nf] = __builtin_amdgcn_mfma_f32_16x16x32_bf16(axr, bwi, S[nf], 0, 0, 0);
    }
  }
}

__global__ __launch_bounds__(256) void mlp(unsigned short* __restrict__ SRb,
                                           unsigned short* __restrict__ SIb,
                                           const unsigned short* __restrict__ WTg,
                                           const float* __restrict__ b1,
                                           const float* __restrict__ b2) {
  __shared__ short As[13824];          // 27,648 B
  __shared__ short Wt[2][96 * WKS];    // 39,936 B
  const int t0 = blockIdx.x, n = blockIdx.y, b = blockIdx.z;
  const int tid = threadIdx.x;
  const int k0 = t0 * 64;
  const int lane = tid & 63, wave = tid >> 6;
  const int l15 = lane & 15, kg = lane >> 4;
  const size_t rowbase = ((size_t)b * D_ + n * BS_) * KPB + k0;

  // ---- stage A: spectrum tile transposed to [mode][ch] bf16 ----
  for (int it = tid; it < 1536; it += 256) {
    int ch = it >> 3, ck = it & 7;
    int chm = (ch < 96) ? ch : ch - 96;
    const unsigned short* src =
        ((ch < 96) ? SRb : SIb) + rowbase + (size_t)chm * KPB + ck * 8;
    ushort8v v = *(const ushort8v*)src;
    int base = (ck * 8) * ASTR + ch;
#pragma unroll
    for (int j = 0; j < 8; ++j) As[base + j * ASTR] = (short)v[j];
  }
  // ---- stage layer-1 weights ----
  {
    const unsigned short* wr = WTg + (size_t)(0 * 16 + 0 * 8 + n) * (96 * WKS);
    const unsigned short* wi = WTg + (size_t)(0 * 16 + 1 * 8 + n) * (96 * WKS);
    for (int it = tid; it < 2496; it += 256) {
      int m = it / 1248;
      int off = (it - m * 1248) * 8;
      *(uint4v*)&Wt[m][off] = *(const uint4v*)((m ? wi : wr) + off);
    }
  }
  __syncthreads();

  // ---- layer 1 ----
  f32x4 P[6], Q[6], R[6], S[6];
#pragma unroll
  for (int nf = 0; nf < 6; ++nf) {
    P[nf] = (f32x4){0.f, 0.f, 0.f, 0.f};
    Q[nf] = (f32x4){0.f, 0.f, 0.f, 0.f};
    R[nf] = (f32x4){0.f, 0.f, 0.f, 0.f};
    S[nf] = (f32x4){0.f, 0.f, 0.f, 0.f};
  }
  do_layer(As, Wt[0], Wt[1], wave, lane, P, Q, R, S);

  f32x4 vr[6], vi[6];
#pragma unroll
  for (int nf = 0; nf < 6; ++nf) {
    int col = nf * 16 + l15;
    float br = b1[(size_t)(0 * NB_ + n) * 96 + col];
    float bi = b1[(size_t)(1 * NB_ + n) * 96 + col];
    vr[nf] = P[nf] - Q[nf];
    vi[nf] = R[nf] + S[nf];
#pragma unroll
    for (int j = 0; j < 4; ++j) {
      vr[nf][j] = fmaxf(vr[nf][j] + br, 0.f);
      vi[nf][j] = fmaxf(vi[nf][j] + bi, 0.f);
    }
  }
  __syncthreads();   // all waves done with layer-1 As/Wt reads

  // scatter o1 into As[mode][k]; restage layer-2 weights
  const int mbase = wave * 16 + kg * 4;
#pragma unroll
  for (int nf = 0; nf < 6; ++nf) {
    int col = nf * 16 + l15;
#pragma unroll
    for (int j = 0; j < 4; ++j) {
      As[(mbase + j) * ASTR + col] = (short)f2bf(vr[nf][j]);
      As[(mbase + j) * ASTR + 96 + col] = (short)f2bf(vi[nf][j]);
    }
  }
  {
    const unsigned short* wr = WTg + (size_t)(1 * 16 + 0 * 8 + n) * (96 * WKS);
    const unsigned short* wi = WTg + (size_t)(1 * 16 + 1 * 8 + n) * (96 * WKS);
    for (int it = tid; it < 2496; it += 256) {
      int m = it / 1248;
      int off = (it - m * 1248) * 8;
      *(uint4v*)&Wt[m][off] = *(const uint4v*)((m ? wi : wr) + off);
    }
  }
  __syncthreads();

  // ---- layer 2 ----
#pragma unroll
  for (int nf = 0; nf < 6; ++nf) {
    P[nf] = (f32x4){0.f, 0.f, 0.f, 0.f};
    Q[nf] = (f32x4){0.f, 0.f, 0.f, 0.f};
    R[nf] = (f32x4){0.f, 0.f, 0.f, 0.f};
    S[nf] = (f32x4){0.f, 0.f, 0.f, 0.f};
  }
  do_layer(As, Wt[0], Wt[1], wave, lane, P, Q, R, S);

#pragma unroll
  for (int nf = 0; nf < 6; ++nf) {
    int col = nf * 16 + l15;
    float br = b2[(size_t)(0 * NB_ + n) * 96 + col];
    float bi = b2[(size_t)(1 * NB_ + n) * 96 + col];
    vr[nf] = P[nf] - Q[nf];
    vi[nf] = R[nf] + S[nf];
#pragma unroll
    for (int j = 0; j < 4; ++j) {
      float a = vr[nf][j] + br;
      float t = fabsf(a) - 0.01f;
      vr[nf][j] = (t > 0.f) ? copysignf(t, a) : 0.f;
      a = vi[nf][j] + bi;
      t = fabsf(a) - 0.01f;
      vi[nf][j] = (t > 0.f) ? copysignf(t, a) : 0.f;
    }
  }
  __syncthreads();   // all waves done reading As (layer-2 A operand)

  // scatter o2 transposed into As2[ch][72 modes]
#pragma unroll
  for (int nf = 0; nf < 6; ++nf) {
    int col = nf * 16 + l15;
    ushort4v pr, pi;
#pragma unroll
    for (int j = 0; j < 4; ++j) {
      pr[j] = f2bf(vr[nf][j]);
      pi[j] = f2bf(vi[nf][j]);
    }
    *(ushort4v*)&As[col * 72 + mbase] = pr;
    *(ushort4v*)&As[(96 + col) * 72 + mbase] = pi;
  }
  __syncthreads();

  // coalesced write-out [ch][modes] -> planes (mask modes >= NMODES)
  for (int it = tid; it < 1536; it += 256) {
    int ch = it >> 3, ck = it & 7;
    int chm = (ch < 96) ? ch : ch - 96;
    ushort8v v = *(const ushort8v*)&As[ch * 72 + ck * 8];
    unsigned short* dst =
        ((ch < 96) ? SRb : SIb) + rowbase + (size_t)chm * KPB + ck * 8;
    if (k0 + ck * 8 + 7 < NMODES) {
      *(ushort8v*)dst = v;
    } else {
#pragma unroll
      for (int j = 0; j < 8; ++j)
        if (k0 + ck * 8 + j < NMODES) dst[j] = v[j];
    }
  }
}

// ---------------------------------------------------------------------------
// Inverse rFFT(4096, ortho) per (b,d); bf16 spectrum in, scaled row into T.
// ---------------------------------------------------------------------------
__global__ __launch_bounds__(256) void fft_inv(const unsigned short* __restrict__ SRb,
                                               const unsigned short* __restrict__ SIb,
                                               float* __restrict__ T) {
  __shared__ float2 Sb[2][2048];
  __shared__ float2 TW[1024];
  const int d = blockIdx.x;
  const int b = blockIdx.y;
  const int tid = threadIdx.x;

  for (int j = tid; j < 1024; j += 256) {
    float s, c;
    sincosf((float)j * (float)(PI_D / 1024.0), &s, &c);
    TW[j] = make_float2(c, s);
  }

  const unsigned short* sr = SRb + ((size_t)b * D_ + d) * KPB;
  const unsigned short* si = SIb + ((size_t)b * D_ + d) * KPB;
  for (int k = tid; k < 2048; k += 256) {
    float2 z;
    if (k == 0) {
      float x0 = bf2f(sr[0]);
      float xm = bf2f(sr[2048]);
      z = make_float2(0.5f * (x0 + xm), 0.5f * (x0 - xm));
    } else {
      float2 Xk = make_float2(bf2f(sr[k]), bf2f(si[k]));
      float2 Xm = make_float2(bf2f(sr[2048 - k]), -bf2f(si[2048 - k]));
      float2 E = make_float2(0.5f * (Xk.x + Xm.x), 0.5f * (Xk.y + Xm.y));
      float2 Dm = make_float2(0.5f * (Xk.x - Xm.x), 0.5f * (Xk.y - Xm.y));
      float s, c;
      sincosf((float)k * (float)(PI_D / 2048.0), &s, &c);
      float2 O = cmulf(make_float2(c, s), Dm);
      z = make_float2(E.x - O.y, E.y + O.x);
    }
    Sb[0][k] = z;
  }
  __syncthreads();

  int src = 0;
  for (int m = 1; m <= 1024; m <<= 1) {
    for (int t = tid; t < 1024; t += 256) {
      int hi = t & ~(m - 1);
      float2 c0 = Sb[src][t];
      float2 c1 = Sb[src][t + 1024];
      float2 sum = make_float2(c0.x + c1.x, c0.y + c1.y);
      float2 dif = make_float2(c0.x - c1.x, c0.y - c1.y);
      Sb[src ^ 1][t + hi] = sum;
      Sb[src ^ 1][t + hi + m] = cmulf(TW[hi], dif);
    }
    src ^= 1;
    __syncthreads();
  }

  float2* tb = (float2*)(T + ((size_t)b * D_ + d) * L_);
  for (int n = tid; n < 2048; n += 256) {
    float2 z = Sb[src][n];
    tb[n] = make_float2(0.03125f * z.x, 0.03125f * z.y);
  }
}

// ---------------------------------------------------------------------------
extern "C" void kernel_launch(void* const* d_in, const int* in_sizes, int n_in,
                              void* d_out, int out_size, void* d_ws, size_t ws_size,
                              hipStream_t stream) {
  (void)in_sizes; (void)n_in; (void)out_size; (void)ws_size;
  const float* x = (const float*)d_in[0];
  const float* w1 = (const float*)d_in[1];
  const float* b1 = (const float*)d_in[2];
  const float* w2 = (const float*)d_in[3];
  const float* b2 = (const float*)d_in[4];
  unsigned short* SRb = (unsigned short*)d_ws;
  unsigned short* SIb = SRb + PLN;
  float* T = (float*)(SIb + PLN);
  unsigned short* WTg = (unsigned short*)(T + (size_t)B_ * D_ * L_);
  float* y = (float*)d_out;

  prep_weights<<<32, 256, 0, stream>>>(w1, w2, WTg);
  transpose_fwd<<<dim3(D_ / 64, L_ / 64, B_), 256, 0, stream>>>(x, T);
  fft_fwd<<<dim3(D_, B_), 256, 0, stream>>>(T, SRb, SIb);
  mlp<<<dim3(33, NB_, B_), 256, 0, stream>>>(SRb, SIb, WTg, b1, b2);
  fft_inv<<<dim3(D_, B_), 256, 0, stream>>>(SRb, SIb, T);
  transpose_add<<<dim3(D_ / 64, L_ / 64, B_), 256, 0, stream>>>(T, x, y);
}

// Round 4
// 462.693 us; speedup vs baseline: 2.7551x; 1.0388x over previous
//
#include <hip/hip_runtime.h>
#include <math.h>

#define B_      8
#define L_      4096
#define D_      768
#define NB_     8
#define BS_     96
#define NMODES  2049
#define KPB     2112                      // bf16 plane mode stride
#define PLN     ((size_t)B_ * D_ * KPB)   // elems per bf16 spectrum plane
#define WKS     104                       // WT row stride (k padded)
#define ASTR    200                       // As row stride in shorts

static const double PI_D = 3.14159265358979323846;

typedef __attribute__((ext_vector_type(8))) short short8v;
typedef __attribute__((ext_vector_type(8))) unsigned short ushort8v;
typedef __attribute__((ext_vector_type(4))) unsigned short ushort4v;
typedef __attribute__((ext_vector_type(4))) unsigned int uint4v;
typedef __attribute__((ext_vector_type(4))) float f32x4;

__device__ __forceinline__ unsigned short f2bf(float f) {
  union { float f; unsigned u; } v; v.f = f;
  unsigned r = v.u + 0x7FFF + ((v.u >> 16) & 1);   // round-nearest-even
  return (unsigned short)(r >> 16);
}
__device__ __forceinline__ float bf2f(unsigned short h) {
  union { unsigned u; float f; } v; v.u = ((unsigned)h) << 16;
  return v.f;
}
__device__ __forceinline__ float2 cmulf(float2 a, float2 b) {
  return make_float2(a.x * b.x - a.y * b.y, a.x * b.y + a.y * b.x);
}

// swizzled As index: 16B chunks XORed by (row>>3)&7 -> conflict-free staging
__device__ __forceinline__ int as_addr(int row, int ch) {
  int c = ch >> 3, o = ch & 7;
  return row * ASTR + (((c ^ ((row >> 3) & 7)) << 3) + o);
}

// ---------------------------------------------------------------------------
// Weight prep: w[k][o] (f32) -> WT[o][k] (bf16, row stride WKS). 32 wgs.
// ---------------------------------------------------------------------------
__global__ __launch_bounds__(256) void prep_weights(const float* __restrict__ w1,
                                                    const float* __restrict__ w2,
                                                    unsigned short* __restrict__ WTg) {
  __shared__ float t[96][97];
  const int id = blockIdx.x;
  const int layer = id >> 4;
  const int hn = id & 15;
  const int tid = threadIdx.x;
  const float* src = (layer ? w2 : w1) + (size_t)hn * 9216;
  for (int it = tid; it < 9216; it += 256) {
    int i = it / 96, o = it - i * 96;
    t[i][o] = src[it];
  }
  __syncthreads();
  unsigned short* dst = WTg + (size_t)id * (96 * WKS);
  for (int it = tid; it < 96 * WKS; it += 256) {
    int o = it / WKS, k = it - o * WKS;
    dst[it] = f2bf(k < 96 ? t[k][o] : 0.f);
  }
}

// ---------------------------------------------------------------------------
// Transpose x (B,L,D) f32 -> T (B,D,L) bf16.
// ---------------------------------------------------------------------------
__global__ __launch_bounds__(256) void transpose_fwd(const float* __restrict__ in,
                                                     unsigned short* __restrict__ out) {
  __shared__ unsigned short tile[64][65];
  const int b = blockIdx.z;
  const int d0 = blockIdx.x * 64;
  const int l0 = blockIdx.y * 64;
  const int tx = threadIdx.x & 63;
  const int ty = threadIdx.x >> 6;
  const float* ib = in + (size_t)b * L_ * D_;
  for (int r = ty; r < 64; r += 4)
    tile[r][tx] = f2bf(ib[(size_t)(l0 + r) * D_ + d0 + tx]);
  __syncthreads();
  unsigned short* ob = out + (size_t)b * D_ * L_;
  for (int r = ty; r < 64; r += 4)
    ob[(size_t)(d0 + r) * L_ + l0 + tx] = tile[tx][r];
}

// ---------------------------------------------------------------------------
// Transpose-back + residual: y[b][l][d] = x[b][l][d] + bf2f(T[b][d][l])
// ---------------------------------------------------------------------------
__global__ __launch_bounds__(256) void transpose_add(const unsigned short* __restrict__ T,
                                                     const float* __restrict__ x,
                                                     float* __restrict__ y) {
  __shared__ unsigned short tile[64][65];
  const int b = blockIdx.z;
  const int d0 = blockIdx.x * 64;
  const int l0 = blockIdx.y * 64;
  const int tx = threadIdx.x & 63;
  const int ty = threadIdx.x >> 6;
  const unsigned short* Tb = T + (size_t)b * D_ * L_;
  for (int r = ty; r < 64; r += 4)
    tile[r][tx] = Tb[(size_t)(d0 + r) * L_ + l0 + tx];
  __syncthreads();
  const float* xb = x + (size_t)b * L_ * D_;
  float* yb = y + (size_t)b * L_ * D_;
  for (int r = ty; r < 64; r += 4) {
    size_t a = (size_t)(l0 + r) * D_ + d0 + tx;
    yb[a] = xb[a] + bf2f(tile[tx][r]);
  }
}

// ---------------------------------------------------------------------------
// Radix-4 Stockham stages (5x radix-4 + 1x radix-2), padded LDS.
// ---------------------------------------------------------------------------
#define FPAD(i) ((i) + ((i) >> 4))

template <int SGN>   // -1 fwd, +1 inv
__device__ __forceinline__ void fft_stages(float2 (*Sb)[2176],
                                           const float2* __restrict__ TW,
                                           int tid, int& src) {
#pragma unroll
  for (int s = 0; s < 5; ++s) {
    const int m = 1 << (2 * s);
    for (int q = tid; q < 512; q += 256) {
      int lo = q & (m - 1);
      int mJ = q - lo;
      float2 x0 = Sb[src][FPAD(q)];
      float2 x1 = Sb[src][FPAD(q + 512)];
      float2 x2 = Sb[src][FPAD(q + 1024)];
      float2 x3 = Sb[src][FPAD(q + 1536)];
      float2 a = make_float2(x0.x + x2.x, x0.y + x2.y);
      float2 bb = make_float2(x0.x - x2.x, x0.y - x2.y);
      float2 c = make_float2(x1.x + x3.x, x1.y + x3.y);
      float2 dd = make_float2(x1.x - x3.x, x1.y - x3.y);
      float2 id = (SGN < 0) ? make_float2(dd.y, -dd.x)    // -i*d
                            : make_float2(-dd.y, dd.x);   // +i*d
      float2 w1 = TW[mJ];
      float2 w2 = TW[2 * mJ];
      float2 w3 = cmulf(w1, w2);
      int ob = 4 * mJ + lo;
      Sb[src ^ 1][FPAD(ob)] = make_float2(a.x + c.x, a.y + c.y);
      Sb[src ^ 1][FPAD(ob + m)] = cmulf(w1, make_float2(bb.x + id.x, bb.y + id.y));
      Sb[src ^ 1][FPAD(ob + 2 * m)] = cmulf(w2, make_float2(a.x - c.x, a.y - c.y));
      Sb[src ^ 1][FPAD(ob + 3 * m)] = cmulf(w3, make_float2(bb.x - id.x, bb.y - id.y));
    }
    src ^= 1;
    __syncthreads();
  }
  for (int t = tid; t < 1024; t += 256) {   // final radix-2 (twiddle = 1)
    float2 c0 = Sb[src][FPAD(t)];
    float2 c1 = Sb[src][FPAD(t + 1024)];
    Sb[src ^ 1][FPAD(t)] = make_float2(c0.x + c1.x, c0.y + c1.y);
    Sb[src ^ 1][FPAD(t + 1024)] = make_float2(c0.x - c1.x, c0.y - c1.y);
  }
  src ^= 1;
  __syncthreads();
}

// ---------------------------------------------------------------------------
// Forward rFFT(4096, ortho) per (b,d) row of bf16 T; bf16 spectrum out.
// ---------------------------------------------------------------------------
__global__ __launch_bounds__(256) void fft_fwd(const unsigned short* __restrict__ T,
                                               unsigned short* __restrict__ SRb,
                                               unsigned short* __restrict__ SIb) {
  __shared__ float2 Sb[2][2176];
  __shared__ float2 TW[1024];
  const int d = blockIdx.x;
  const int b = blockIdx.y;
  const int tid = threadIdx.x;

  for (int j = tid; j < 1024; j += 256) {
    float s, c;
    sincosf(-(float)j * (float)(PI_D / 1024.0), &s, &c);
    TW[j] = make_float2(c, s);
  }

  const ushort8v* tb = (const ushort8v*)(T + ((size_t)b * D_ + d) * L_);
  for (int it = tid; it < 512; it += 256) {
    ushort8v v = tb[it];
    int base = it * 4;
#pragma unroll
    for (int c = 0; c < 4; ++c)
      Sb[0][FPAD(base + c)] = make_float2(bf2f(v[2 * c]), bf2f(v[2 * c + 1]));
  }
  __syncthreads();

  int src = 0;
  fft_stages<-1>(Sb, TW, tid, src);

  unsigned short* sr = SRb + ((size_t)b * D_ + d) * KPB;
  unsigned short* si = SIb + ((size_t)b * D_ + d) * KPB;
  for (int k = tid; k <= 2048; k += 256) {
    int ia = k & 2047;
    int ib = (2048 - k) & 2047;
    float2 Za = Sb[src][FPAD(ia)];
    float2 Zb = Sb[src][FPAD(ib)];
    Zb.y = -Zb.y;
    float2 sum = make_float2(0.5f * (Za.x + Zb.x), 0.5f * (Za.y + Zb.y));
    float2 dif = make_float2(0.5f * (Za.x - Zb.x), 0.5f * (Za.y - Zb.y));
    float s, c;
    sincosf(-(float)k * (float)(PI_D / 2048.0), &s, &c);
    float2 t = cmulf(make_float2(c, s), dif);
    sr[k] = f2bf((sum.x + t.y) * 0.015625f);
    si[k] = f2bf((sum.y - t.x) * 0.015625f);
  }
}

// ---------------------------------------------------------------------------
// MFMA MLP: swizzled A staging, direct-global epilogue.
// ---------------------------------------------------------------------------
__device__ __forceinline__ void do_layer(const short* As, const short* Wt0,
                                         const short* Wt1, int wave, int lane,
                                         f32x4 P[6], f32x4 Q[6], f32x4 R[6],
                                         f32x4 S[6]) {
  const int l15 = lane & 15, kg = lane >> 4;
  const int arow = (wave * 16 + l15) * ASTR;
  const int r3 = ((wave * 16 + l15) >> 3) & 7;
#pragma unroll
  for (int ks = 0; ks < 3; ++ks) {
    const int cr = ks * 4 + kg;
    short8v axr = *(const short8v*)&As[arow + (((cr ^ r3) << 3))];
    short8v axi = *(const short8v*)&As[arow + ((((cr + 12) ^ r3) << 3))];
    const int ak = ks * 32 + kg * 8;
#pragma unroll
    for (int nf = 0; nf < 6; ++nf) {
      const int brow = (nf * 16 + l15) * WKS + ak;
      short8v bwr = *(const short8v*)&Wt0[brow];
      short8v bwi = *(const short8v*)&Wt1[brow];
      P[nf] = __builtin_amdgcn_mfma_f32_16x16x32_bf16(axr, bwr, P[nf], 0, 0, 0);
      Q[nf] = __builtin_amdgcn_mfma_f32_16x16x32_bf16(axi, bwi, Q[nf], 0, 0, 0);
      R[nf] = __builtin_amdgcn_mfma_f32_16x16x32_bf16(axi, bwr, R[nf], 0, 0, 0);
      S[nf] = __builtin_amdgcn_mfma_f32_16x16x32_bf16(axr, bwi, S[nf], 0, 0, 0);
    }
  }
}

__global__ __launch_bounds__(256) void mlp(unsigned short* __restrict__ SRb,
                                           unsigned short* __restrict__ SIb,
                                           const unsigned short* __restrict__ WTg,
                                           const float* __restrict__ b1,
                                           const float* __restrict__ b2) {
  __shared__ short As[64 * ASTR];      // 25.6 KB, swizzled [mode][ch]
  __shared__ short Wt[2][96 * WKS];    // 39.9 KB
  const int t0 = blockIdx.x, n = blockIdx.y, b = blockIdx.z;
  const int tid = threadIdx.x;
  const int k0 = t0 * 64;
  const int lane = tid & 63, wave = tid >> 6;
  const int l15 = lane & 15, kg = lane >> 4;
  const size_t rowbase = ((size_t)b * D_ + n * BS_) * KPB + k0;

  // ---- stage A: [ch][mode] global -> swizzled [mode][ch] LDS ----
  for (int it = tid; it < 1536; it += 256) {
    int ch = it >> 3, ck = it & 7;
    int chm = (ch < 96) ? ch : ch - 96;
    const unsigned short* src =
        ((ch < 96) ? SRb : SIb) + rowbase + (size_t)chm * KPB + ck * 8;
    ushort8v v = *(const ushort8v*)src;
#pragma unroll
    for (int j = 0; j < 8; ++j) As[as_addr(ck * 8 + j, ch)] = (short)v[j];
  }
  // ---- stage layer-1 weights ----
  {
    const unsigned short* wr = WTg + (size_t)(0 * 16 + 0 * 8 + n) * (96 * WKS);
    const unsigned short* wi = WTg + (size_t)(0 * 16 + 1 * 8 + n) * (96 * WKS);
    for (int it = tid; it < 2496; it += 256) {
      int m = it / 1248;
      int off = (it - m * 1248) * 8;
      *(uint4v*)&Wt[m][off] = *(const uint4v*)((m ? wi : wr) + off);
    }
  }
  __syncthreads();

  // ---- layer 1 ----
  f32x4 P[6], Q[6], R[6], S[6];
#pragma unroll
  for (int nf = 0; nf < 6; ++nf) {
    P[nf] = (f32x4){0.f, 0.f, 0.f, 0.f};
    Q[nf] = (f32x4){0.f, 0.f, 0.f, 0.f};
    R[nf] = (f32x4){0.f, 0.f, 0.f, 0.f};
    S[nf] = (f32x4){0.f, 0.f, 0.f, 0.f};
  }
  do_layer(As, Wt[0], Wt[1], wave, lane, P, Q, R, S);

  f32x4 vr[6], vi[6];
#pragma unroll
  for (int nf = 0; nf < 6; ++nf) {
    int col = nf * 16 + l15;
    float br = b1[(size_t)n * 96 + col];
    float bi = b1[(size_t)(NB_ + n) * 96 + col];
    vr[nf] = P[nf] - Q[nf];
    vi[nf] = R[nf] + S[nf];
#pragma unroll
    for (int j = 0; j < 4; ++j) {
      vr[nf][j] = fmaxf(vr[nf][j] + br, 0.f);
      vi[nf][j] = fmaxf(vi[nf][j] + bi, 0.f);
    }
  }
  __syncthreads();   // all waves done with layer-1 As reads

  // scatter o1 into swizzled As[mode][k]; restage layer-2 weights
  const int mbase = wave * 16 + kg * 4;
#pragma unroll
  for (int nf = 0; nf < 6; ++nf) {
    int col = nf * 16 + l15;
#pragma unroll
    for (int j = 0; j < 4; ++j) {
      As[as_addr(mbase + j, col)] = (short)f2bf(vr[nf][j]);
      As[as_addr(mbase + j, 96 + col)] = (short)f2bf(vi[nf][j]);
    }
  }
  {
    const unsigned short* wr = WTg + (size_t)(1 * 16 + 0 * 8 + n) * (96 * WKS);
    const unsigned short* wi = WTg + (size_t)(1 * 16 + 1 * 8 + n) * (96 * WKS);
    for (int it = tid; it < 2496; it += 256) {
      int m = it / 1248;
      int off = (it - m * 1248) * 8;
      *(uint4v*)&Wt[m][off] = *(const uint4v*)((m ? wi : wr) + off);
    }
  }
  __syncthreads();

  // ---- layer 2 ----
#pragma unroll
  for (int nf = 0; nf < 6; ++nf) {
    P[nf] = (f32x4){0.f, 0.f, 0.f, 0.f};
    Q[nf] = (f32x4){0.f, 0.f, 0.f, 0.f};
    R[nf] = (f32x4){0.f, 0.f, 0.f, 0.f};
    S[nf] = (f32x4){0.f, 0.f, 0.f, 0.f};
  }
  do_layer(As, Wt[0], Wt[1], wave, lane, P, Q, R, S);

  // bias + softshrink + DIRECT global store (lane holds 4 consecutive modes)
  const int mk = k0 + mbase;
#pragma unroll
  for (int nf = 0; nf < 6; ++nf) {
    int col = nf * 16 + l15;
    float br = b2[(size_t)n * 96 + col];
    float bi = b2[(size_t)(NB_ + n) * 96 + col];
    ushort4v qr, qi;
#pragma unroll
    for (int j = 0; j < 4; ++j) {
      float a = (P[nf][j] - Q[nf][j]) + br;
      float t = fabsf(a) - 0.01f;
      qr[j] = f2bf((t > 0.f) ? copysignf(t, a) : 0.f);
      a = (R[nf][j] + S[nf][j]) + bi;
      t = fabsf(a) - 0.01f;
      qi[j] = f2bf((t > 0.f) ? copysignf(t, a) : 0.f);
    }
    unsigned short* pr = SRb + rowbase + (size_t)col * KPB + mbase;
    unsigned short* pi = SIb + rowbase + (size_t)col * KPB + mbase;
    if (mk + 3 < NMODES) {
      *(ushort4v*)pr = qr;
      *(ushort4v*)pi = qi;
    } else {
#pragma unroll
      for (int j = 0; j < 4; ++j)
        if (mk + j < NMODES) { pr[j] = qr[j]; pi[j] = qi[j]; }
    }
  }
}

// ---------------------------------------------------------------------------
// Inverse rFFT(4096, ortho) per (b,d); bf16 spectrum in, bf16 row into T.
// ---------------------------------------------------------------------------
__global__ __launch_bounds__(256) void fft_inv(const unsigned short* __restrict__ SRb,
                                               const unsigned short* __restrict__ SIb,
                                               unsigned short* __restrict__ T) {
  __shared__ float2 Sb[2][2176];
  __shared__ float2 TW[1024];
  const int d = blockIdx.x;
  const int b = blockIdx.y;
  const int tid = threadIdx.x;

  for (int j = tid; j < 1024; j += 256) {
    float s, c;
    sincosf((float)j * (float)(PI_D / 1024.0), &s, &c);
    TW[j] = make_float2(c, s);
  }

  const unsigned short* sr = SRb + ((size_t)b * D_ + d) * KPB;
  const unsigned short* si = SIb + ((size_t)b * D_ + d) * KPB;
  for (int k = tid; k < 2048; k += 256) {
    float2 z;
    if (k == 0) {
      float x0 = bf2f(sr[0]);
      float xm = bf2f(sr[2048]);
      z = make_float2(0.5f * (x0 + xm), 0.5f * (x0 - xm));
    } else {
      float2 Xk = make_float2(bf2f(sr[k]), bf2f(si[k]));
      float2 Xm = make_float2(bf2f(sr[2048 - k]), -bf2f(si[2048 - k]));
      float2 E = make_float2(0.5f * (Xk.x + Xm.x), 0.5f * (Xk.y + Xm.y));
      float2 Dm = make_float2(0.5f * (Xk.x - Xm.x), 0.5f * (Xk.y - Xm.y));
      float s, c;
      sincosf((float)k * (float)(PI_D / 2048.0), &s, &c);
      float2 O = cmulf(make_float2(c, s), Dm);
      z = make_float2(E.x - O.y, E.y + O.x);
    }
    Sb[0][FPAD(k)] = z;
  }
  __syncthreads();

  int src = 0;
  fft_stages<+1>(Sb, TW, tid, src);

  ushort8v* tb = (ushort8v*)(T + ((size_t)b * D_ + d) * L_);
  for (int it = tid; it < 512; it += 256) {
    ushort8v v;
    int base = it * 4;
#pragma unroll
    for (int c = 0; c < 4; ++c) {
      float2 z = Sb[src][FPAD(base + c)];
      v[2 * c] = f2bf(0.03125f * z.x);
      v[2 * c + 1] = f2bf(0.03125f * z.y);
    }
    tb[it] = v;
  }
}

// ---------------------------------------------------------------------------
extern "C" void kernel_launch(void* const* d_in, const int* in_sizes, int n_in,
                              void* d_out, int out_size, void* d_ws, size_t ws_size,
                              hipStream_t stream) {
  (void)in_sizes; (void)n_in; (void)out_size; (void)ws_size;
  const float* x = (const float*)d_in[0];
  const float* w1 = (const float*)d_in[1];
  const float* b1 = (const float*)d_in[2];
  const float* w2 = (const float*)d_in[3];
  const float* b2 = (const float*)d_in[4];
  unsigned short* SRb = (unsigned short*)d_ws;
  unsigned short* SIb = SRb + PLN;
  unsigned short* T = SIb + PLN;                       // bf16 (B,D,L)
  unsigned short* WTg = T + (size_t)B_ * D_ * L_;
  float* y = (float*)d_out;

  prep_weights<<<32, 256, 0, stream>>>(w1, w2, WTg);
  transpose_fwd<<<dim3(D_ / 64, L_ / 64, B_), 256, 0, stream>>>(x, T);
  fft_fwd<<<dim3(D_, B_), 256, 0, stream>>>(T, SRb, SIb);
  mlp<<<dim3(33, NB_, B_), 256, 0, stream>>>(SRb, SIb, WTg, b1, b2);
  fft_inv<<<dim3(D_, B_), 256, 0, stream>>>(SRb, SIb, T);
  transpose_add<<<dim3(D_ / 64, L_ / 64, B_), 256, 0, stream>>>(T, x, y);
}